// Round 9
// baseline (827.132 us; speedup 1.0000x reference)
//
#include <hip/hip_runtime.h>
#include <hip/hip_bf16.h>
#include <math.h>

#define T_LEN 8192
#define D_DIM 1024
#define H_DIM 512
#define NPATCH 512
#define SEG 16

typedef _Float16 f16;
typedef _Float16 f16x4 __attribute__((ext_vector_type(4)));
typedef _Float16 f16x8 __attribute__((ext_vector_type(8)));
typedef float f32x4 __attribute__((ext_vector_type(4)));

// ---------------- constants ----------------
#define BMR 256            // block rows (t)
#define BNR 128            // block cols (h)
#define NBM2 128           // 32768/256
#define NBN2 4             // 512/128
#define QL2 258            // per-block partial logit slice
#define PADT (T_LEN + 2)   // zero-padded rows per batch
#define RSCALE 2048.0f     // residual scale 2^11 (keeps lo-parts f16-normal)
#define RINV   4.8828125e-4f  // 1/2048

#define ABUFB 32768        // per-buffer LDS: A_hi [256][32] @0, A_lo @16384
#define NSTEP 96           // 3 taps * 32 k-steps
#define BJUMP ((uint32_t)(2 * H_DIM * D_DIM - 992) * 2)   // B byte delta at tap boundary

__device__ __forceinline__ void gll16(const void* g, void* l) {
    __builtin_amdgcn_global_load_lds((const __attribute__((address_space(1))) void*)g,
                                     (__attribute__((address_space(3))) void*)l, 16, 0, 0);
}

// ---------------- K_a: split x (fp32 -> hi f16 + scaled-lo f16, zero-padded rows) ----
__global__ __launch_bounds__(256) void k_split_x(const float* __restrict__ x,
                                                 f16* __restrict__ xh, f16* __restrict__ xls) {
    size_t i4 = (size_t)blockIdx.x * 256 + threadIdx.x;   // unit of 4 elements
    size_t e = i4 * 4;
    int d = (int)(e % D_DIM);
    size_t row = e / D_DIM;
    int pt = (int)(row % PADT);
    int b = (int)(row / PADT);
    f16x4 h, lo;
    if (pt == 0 || pt == PADT - 1) {
        h = (f16x4){0, 0, 0, 0}; lo = (f16x4){0, 0, 0, 0};
    } else {
        float4 v = *(const float4*)(x + ((size_t)b * T_LEN + pt - 1) * D_DIM + d);
        f16 h0 = (f16)v.x, h1 = (f16)v.y, h2 = (f16)v.z, h3 = (f16)v.w;
        h = (f16x4){h0, h1, h2, h3};
        lo = (f16x4){(f16)((v.x - (float)h0) * RSCALE), (f16)((v.y - (float)h1) * RSCALE),
                     (f16)((v.z - (float)h2) * RSCALE), (f16)((v.w - (float)h3) * RSCALE)};
    }
    *(f16x4*)(xh + e) = h;
    *(f16x4*)(xls + e) = lo;
}

// ---------------- K_b: split conv1_w (h,D,3) -> ws[j][hi/lo][o][i] f16 (lo scaled) ----
__global__ void k_split_w(const float* __restrict__ w1, f16* __restrict__ ws) {
    int idx = blockIdx.x * 256 + threadIdx.x;   // over 3*512*1024
    if (idx >= 3 * H_DIM * D_DIM) return;
    int i = idx % D_DIM;
    int o = (idx / D_DIM) % H_DIM;
    int j = idx / (D_DIM * H_DIM);
    float v = w1[((size_t)o * D_DIM + i) * 3 + j];
    f16 h = (f16)v;
    f16 l = (f16)((v - (float)h) * RSCALE);
    ws[((size_t)(j * 2 + 0) * H_DIM + o) * D_DIM + i] = h;
    ws[((size_t)(j * 2 + 1) * H_DIM + o) * D_DIM + i] = l;
}

// ---------------- K_c: MFMA f16-split conv1 + GELU + conv2 partials ----------------
// 8 waves (512 thr), __launch_bounds__(512, 1): 1 block/CU min -> 2 waves/EU ->
// VGPR cap 256 (the (512,2) variant capped at 128 and spilled ~110 regs/thread:
// WRITE_SIZE 907MB, 835us. Structure identical to that correctness-verified run).
// Block 256x128, wave tile 64x64, 16x16x32 MFMA.
// A: triple-buffered LDS (3 x 32KB, chunk-XOR swizzle, global_load_lds).
// B: DIRECT global->VGPR fragment loads from L2 (no LDS stage), double-buffered
//    regs, loaded one full step ahead.
// Per step: [8 B(t+1) reg loads][4 A(t+2) gll16][8 ds_read A(t)][48 MFMA]
//           [vmcnt(12): A(t+1) landed, B(t+1)+A(t+2) in flight][barrier]
#define MM3(mi, nj, AH, AL, BH, BL)                                                       \
    ahh[mi][nj] = __builtin_amdgcn_mfma_f32_16x16x32_f16(AH, BH, ahh[mi][nj], 0, 0, 0);   \
    axx[mi][nj] = __builtin_amdgcn_mfma_f32_16x16x32_f16(AH, BL, axx[mi][nj], 0, 0, 0);   \
    axx[mi][nj] = __builtin_amdgcn_mfma_f32_16x16x32_f16(AL, BH, axx[mi][nj], 0, 0, 0);

#define LOADB(BH_, BL_)                                                                   \
    { _Pragma("unroll")                                                                   \
      for (int q = 0; q < 4; ++q) BH_[q] = *(const f16x8*)((const char*)wsd + boff[q]);   \
      _Pragma("unroll")                                                                   \
      for (int q = 0; q < 4; ++q) BL_[q] = *(const f16x8*)((const char*)wsd + boff[4+q]); }

#define ADVB(SNEXT_)                                                                      \
    { uint32_t d_ = ((((SNEXT_)) & 31) == 0) ? BJUMP : 64u;                               \
      _Pragma("unroll")                                                                   \
      for (int q = 0; q < 8; ++q) boff[q] += d_; }

// body only; caller appends wait + barrier
#define GBODY(T_, ABUF_, DBUF_, BCH_, BCL_, BNH_, BNL_, DOB_, DOA_)                       \
{                                                                                         \
    if (DOB_) { LOADB(BNH_, BNL_); ADVB((T_) + 2); }                                      \
    if (DOA_) {                                                                           \
        char* dsty_ = (DBUF_);                                                            \
        _Pragma("unroll")                                                                 \
        for (int u = 0; u < 4; ++u) {                                                     \
            gll16((const char*)abase + aoffg[u], dsty_ + (wv * 4 + u) * 1024);            \
            aoffg[u] += 64;                                                               \
        }                                                                                 \
    }                                                                                     \
    char* buf_ = (ABUF_);                                                                 \
    f16x8 ah0, al0, ah1, al1, ah2, al2, ah3, al3;                                         \
    ah0 = *(const f16x8*)(buf_ + aoff_[0]);  al0 = *(const f16x8*)(buf_ + 16384 + aoff_[0]); \
    ah1 = *(const f16x8*)(buf_ + aoff_[1]);  al1 = *(const f16x8*)(buf_ + 16384 + aoff_[1]); \
    ah2 = *(const f16x8*)(buf_ + aoff_[2]);  al2 = *(const f16x8*)(buf_ + 16384 + aoff_[2]); \
    ah3 = *(const f16x8*)(buf_ + aoff_[3]);  al3 = *(const f16x8*)(buf_ + 16384 + aoff_[3]); \
    __builtin_amdgcn_s_setprio(1);                                                        \
    MM3(0, 0, ah0, al0, BCH_[0], BCL_[0]); MM3(0, 1, ah0, al0, BCH_[1], BCL_[1]);         \
    MM3(1, 0, ah1, al1, BCH_[0], BCL_[0]); MM3(1, 1, ah1, al1, BCH_[1], BCL_[1]);         \
    MM3(2, 0, ah2, al2, BCH_[0], BCL_[0]); MM3(2, 1, ah2, al2, BCH_[1], BCL_[1]);         \
    MM3(3, 0, ah3, al3, BCH_[0], BCL_[0]); MM3(3, 1, ah3, al3, BCH_[1], BCL_[1]);         \
    MM3(2, 2, ah2, al2, BCH_[2], BCL_[2]); MM3(2, 3, ah2, al2, BCH_[3], BCL_[3]);         \
    MM3(3, 2, ah3, al3, BCH_[2], BCL_[2]); MM3(3, 3, ah3, al3, BCH_[3], BCL_[3]);         \
    MM3(0, 2, ah0, al0, BCH_[2], BCL_[2]); MM3(0, 3, ah0, al0, BCH_[3], BCL_[3]);         \
    MM3(1, 2, ah1, al1, BCH_[2], BCL_[2]); MM3(1, 3, ah1, al1, BCH_[3], BCL_[3]);         \
    __builtin_amdgcn_s_setprio(0);                                                        \
}

#define WAIT12 asm volatile("s_waitcnt vmcnt(12)" ::: "memory")
#define WAIT8  asm volatile("s_waitcnt vmcnt(8)"  ::: "memory")
#define BAR    __builtin_amdgcn_s_barrier()

__global__ __launch_bounds__(512, 1) void k_conv_gemm_f16(
    const f16* __restrict__ xh, const f16* __restrict__ xls,
    const f16* __restrict__ wsd, const float* __restrict__ b1,
    const float* __restrict__ w2, float* __restrict__ partials)
{
    __shared__ __align__(16) char smem[3 * ABUFB + 6144];   // 104448 B
    const int tid = threadIdx.x;
    const int l = tid & 63, wv = tid >> 6;        // 8 waves
    const int wr = wv >> 1, wc = wv & 1;

    // XCD-bijective swizzle (512 blocks = 8 XCD * 64); 4 bn-blocks sharing an A tile
    // land on one XCD for L2 reuse.
    int bid = blockIdx.x;
    int logical = (bid & 7) * 64 + (bid >> 3);
    const int bm = logical >> 2, bn = logical & 3;
    const int batch = bm >> 5;
    const int lt0 = (bm & 31) * BMR;
    const int n0 = bn * BNR;

    f32x4 ahh[4][4], axx[4][4];
    #pragma unroll
    for (int mi = 0; mi < 4; ++mi)
        #pragma unroll
        for (int nj = 0; nj < 4; ++nj) {
            ahh[mi][nj] = (f32x4){0.f, 0.f, 0.f, 0.f};
            axx[mi][nj] = (f32x4){0.f, 0.f, 0.f, 0.f};
        }

    const int kb = l >> 4, c15 = l & 15;

    // ---- A staging: 4 slots/wave; slot S = wv*4+u; dst = buf + S*1024 (+ lane*16) ----
    const f16* abase = (wv < 4) ? xh : xls;
    uint32_t aoffg[4];
    #pragma unroll
    for (int u = 0; u < 4; ++u) {
        int S = wv * 4 + u;
        int sl = S & 15;
        int m = sl * 16 + (l >> 2);
        int ch = (l & 3) ^ ((m >> 1) & 3);
        aoffg[u] = (uint32_t)(((((uint32_t)batch * PADT + lt0 + m) * D_DIM) + ch * 8) * 2);
    }

    // ---- B direct-load byte offsets (j=0, k0=0): frag (part p, nj) ----
    uint32_t boff[8];
    #pragma unroll
    for (int p = 0; p < 2; ++p)
        #pragma unroll
        for (int nj = 0; nj < 4; ++nj) {
            int n = n0 + wc * 64 + nj * 16 + c15;
            boff[p * 4 + nj] = (uint32_t)(((((uint32_t)p * H_DIM + n) * D_DIM) + kb * 8) * 2);
        }

    // ---- per-frag LDS byte offsets for A ds_reads (t-invariant) ----
    int aoff_[4];
    #pragma unroll
    for (int mi = 0; mi < 4; ++mi) {
        int m = wr * 64 + mi * 16 + c15;
        aoff_[mi] = m * 64 + ((kb ^ ((m >> 1) & 3)) * 16);
    }

    char* A0 = smem;
    char* A1 = smem + ABUFB;
    char* A2 = smem + 2 * ABUFB;

    f16x8 bAh[4], bAl[4], bBh[4], bBl[4];

    // prologue: A(0)->buf0, A(1)->buf1, B(0)->set A
    #pragma unroll
    for (int u = 0; u < 4; ++u)
        gll16((const char*)abase + aoffg[u], A0 + (wv * 4 + u) * 1024);
    #pragma unroll
    for (int u = 0; u < 4; ++u) {
        gll16((const char*)abase + aoffg[u] + 64, A1 + (wv * 4 + u) * 1024);
        aoffg[u] += 128;                       // points at t=2
    }
    LOADB(bAh, bAl);                           // B(0)
    ADVB(1);                                   // advance to B(1)
    WAIT12;                                    // A(0) landed (A(1)+B(0)=12 in flight)
    BAR;

    for (int tt = 0; tt < 90; tt += 6) {
        GBODY(tt + 0, A0, A2, bAh, bAl, bBh, bBl, 1, 1); WAIT12; BAR;
        GBODY(tt + 1, A1, A0, bBh, bBl, bAh, bAl, 1, 1); WAIT12; BAR;
        GBODY(tt + 2, A2, A1, bAh, bAl, bBh, bBl, 1, 1); WAIT12; BAR;
        GBODY(tt + 3, A0, A2, bBh, bBl, bAh, bAl, 1, 1); WAIT12; BAR;
        GBODY(tt + 4, A1, A0, bAh, bAl, bBh, bBl, 1, 1); WAIT12; BAR;
        GBODY(tt + 5, A2, A1, bBh, bBl, bAh, bAl, 1, 1); WAIT12; BAR;
    }
    // peeled tail: t = 90..95
    GBODY(90, A0, A2, bAh, bAl, bBh, bBl, 1, 1); WAIT12; BAR;
    GBODY(91, A1, A0, bBh, bBl, bAh, bAl, 1, 1); WAIT12; BAR;
    GBODY(92, A2, A1, bAh, bAl, bBh, bBl, 1, 1); WAIT12; BAR;
    GBODY(93, A0, A2, bBh, bBl, bAh, bAl, 1, 1); WAIT12; BAR;
    GBODY(94, A1, A0, bAh, bAl, bBh, bBl, 1, 0); WAIT8;  BAR;   // B(95) only
    GBODY(95, A2, A1, bBh, bBl, bAh, bAl, 0, 0);         BAR;   // drain

    // epilogue: combine hh + cross*2^-11, bias + exact GELU + conv2 tap fold
    float* lp_lds = (float*)(smem + 3 * ABUFB);   // [wc][d][m] = [2][3][256]
    #pragma unroll
    for (int mi = 0; mi < 4; ++mi) {
        float lp[4][3] = {};
        #pragma unroll
        for (int nj = 0; nj < 4; ++nj) {
            int n = n0 + wc * 64 + nj * 16 + c15;
            float bias = b1[n];
            float w2m1 = w2[n * 3 + 2];   // hcv[t] -> logits[t-1]
            float w20  = w2[n * 3 + 1];
            float w2p1 = w2[n * 3 + 0];
            #pragma unroll
            for (int r = 0; r < 4; ++r) {
                float v = ahh[mi][nj][r] + axx[mi][nj][r] * RINV + bias;
                float g = 0.5f * v * (1.f + erff(v * 0.70710678118654752f));
                lp[r][0] = fmaf(g, w2m1, lp[r][0]);
                lp[r][1] = fmaf(g, w20,  lp[r][1]);
                lp[r][2] = fmaf(g, w2p1, lp[r][2]);
            }
        }
        #pragma unroll
        for (int r = 0; r < 4; ++r)
            #pragma unroll
            for (int d = 0; d < 3; ++d) {
                float v = lp[r][d];
                v += __shfl_xor(v, 1, 64);
                v += __shfl_xor(v, 2, 64);
                v += __shfl_xor(v, 4, 64);
                v += __shfl_xor(v, 8, 64);
                lp[r][d] = v;
            }
        if (c15 == 0) {
            int m = wr * 64 + mi * 16 + kb * 4;
            #pragma unroll
            for (int r = 0; r < 4; ++r)
                #pragma unroll
                for (int d = 0; d < 3; ++d)
                    lp_lds[(wc * 3 + d) * 256 + m + r] = lp[r][d];
        }
    }
    __syncthreads();

    float* pout = partials + (size_t)(bm * NBN2 + bn) * QL2;
    for (int q = tid; q < QL2; q += 512) {
        int tloc = lt0 + q - 1;
        if (tloc >= 0 && tloc < T_LEN) {
            float v = 0.f;
            #pragma unroll
            for (int w2c = 0; w2c < 2; ++w2c) {
                if (q >= 1 && q <= 256) v += lp_lds[(w2c * 3 + 1) * 256 + q - 1];
                if (q >= 2)             v += lp_lds[(w2c * 3 + 2) * 256 + q - 2];
                if (q < 256)            v += lp_lds[(w2c * 3 + 0) * 256 + q];
            }
            pout[q] = v;
        }
    }
}

// ---------------- K_d: deterministic logit reduction (256-row blocks) ----------------
__global__ void k_reduce2(const float* __restrict__ partials,
                          const float* __restrict__ b2, float* __restrict__ logits) {
    int M = blockIdx.x * 256 + threadIdx.x;
    if (M >= 4 * T_LEN) return;
    int t = M & (T_LEN - 1);
    int bm = M >> 8;
    int mq = M & 255;
    int q = mq + 1;
    float s = b2[0];
    #pragma unroll
    for (int bn = 0; bn < NBN2; ++bn)
        s += partials[(size_t)(bm * NBN2 + bn) * QL2 + q];
    if (mq == 0 && t != 0) {
        #pragma unroll
        for (int bn = 0; bn < NBN2; ++bn)
            s += partials[(size_t)((bm - 1) * NBN2 + bn) * QL2 + (QL2 - 1)];
    }
    if (mq == 255 && t != T_LEN - 1) {
        #pragma unroll
        for (int bn = 0; bn < NBN2; ++bn)
            s += partials[(size_t)((bm + 1) * NBN2 + bn) * QL2 + 0];
    }
    logits[M] = s;
}

// ---------------- K3: softmax/centroid/entropy + gather + RMSNorm ----------------
__global__ __launch_bounds__(256) void k_finalize(
    const float* __restrict__ x, const float* __restrict__ logits,
    const float* __restrict__ norm_w, float* __restrict__ out)
{
    int blk = blockIdx.x;            // 0..2047
    int b = blk >> 9, p = blk & 511;
    const float* lg = logits + b * T_LEN + p * SEG;

    float l[SEG];
    #pragma unroll
    for (int i = 0; i < SEG; ++i) l[i] = lg[i];
    float mx = l[0];
    #pragma unroll
    for (int i = 1; i < SEG; ++i) mx = fmaxf(mx, l[i]);
    float w[SEG];
    float s = 0.f;
    #pragma unroll
    for (int i = 0; i < SEG; ++i) { w[i] = expf(l[i] - mx); s += w[i]; }
    float inv = 1.f / s;
    float boundary = 0.f, ent = 0.f;
    #pragma unroll
    for (int i = 0; i < SEG; ++i) {
        float wi = w[i] * inv;
        boundary += wi * (float)(p * SEG + i);
        ent -= wi * logf(fmaxf(wi, 1e-8f));
    }
    ent *= 0.36067376022224085f;     // 1 / log(16)

    int idx = (int)boundary;
    idx = min(max(idx, 0), T_LEN - 1);

    const float* row = x + ((size_t)b * T_LEN + idx) * D_DIM;
    int tid = threadIdx.x;
    float v[4];
    float ss = 0.f;
    #pragma unroll
    for (int r = 0; r < 4; ++r) {
        int c = tid + r * 256;
        v[r] = row[c];
        ss = fmaf(v[r], v[r], ss);
    }
    #pragma unroll
    for (int off = 32; off > 0; off >>= 1) ss += __shfl_down(ss, off, 64);
    __shared__ float sred[4];
    if ((tid & 63) == 0) sred[tid >> 6] = ss;
    __syncthreads();
    float tot = sred[0] + sred[1] + sred[2] + sred[3];
    float rms = rsqrtf(tot * (1.f / 1024.f) + 1e-6f);

    float* o0 = out + ((size_t)b * NPATCH + p) * D_DIM;
    #pragma unroll
    for (int r = 0; r < 4; ++r) {
        int c = tid + r * 256;
        o0[c] = v[r] * rms * norm_w[c];
    }
    if (tid == 0)
        out[(size_t)4 * NPATCH * D_DIM + b * NPATCH + p] = ent;
}

// ==================== fallback (round-1 fp32 path, known-passing) ====================
#define BM 128
#define BN 128
#define BK 16
#define NBM (4 * T_LEN / BM)
#define NBN (H_DIM / BN)
#define QLEN 130

__global__ void k_transpose_w1(const float* __restrict__ w1, float* __restrict__ w1t) {
    int idx = blockIdx.x * 256 + threadIdx.x;
    if (idx >= 3 * D_DIM * H_DIM) return;
    int o = idx % H_DIM;
    int i = (idx / H_DIM) % D_DIM;
    int j = idx / (H_DIM * D_DIM);
    w1t[idx] = w1[(o * D_DIM + i) * 3 + j];
}

__global__ __launch_bounds__(256) void k_conv_gemm(
    const float* __restrict__ x, const float* __restrict__ w1t,
    const float* __restrict__ b1, const float* __restrict__ w2,
    float* __restrict__ partials)
{
    __shared__ float As[BK][BM + 4];
    __shared__ float Bs[BK][BN];
    __shared__ float ld_lp[3][BM];

    const int bm = blockIdx.x, bn = blockIdx.y;
    const int m0 = bm * BM;
    const int batch = m0 / T_LEN;
    const int t0 = m0 % T_LEN;
    const int n0 = bn * BN;
    const int tid = threadIdx.x;
    const int tx = tid & 15, ty = tid >> 4;

    float acc[8][8] = {};

    const int a_col = (tid & 3) * 4;
    const int a_row = tid >> 2;
    const int b_row = tid >> 5;
    const int b_col = (tid & 31) * 4;

    const float* xb = x + (size_t)batch * T_LEN * D_DIM;

    for (int j = 0; j < 3; ++j) {
        const float* wj = w1t + (size_t)j * D_DIM * H_DIM;
        const int tshift = j - 1;
        for (int k0 = 0; k0 < D_DIM; k0 += BK) {
            #pragma unroll
            for (int rr = 0; rr < 2; ++rr) {
                int m = a_row + rr * 64;
                int tt = t0 + m + tshift;
                float4 v = make_float4(0.f, 0.f, 0.f, 0.f);
                if (tt >= 0 && tt < T_LEN)
                    v = *(const float4*)(xb + (size_t)tt * D_DIM + k0 + a_col);
                As[a_col + 0][m] = v.x; As[a_col + 1][m] = v.y;
                As[a_col + 2][m] = v.z; As[a_col + 3][m] = v.w;
            }
            #pragma unroll
            for (int rr = 0; rr < 2; ++rr) {
                int kk = b_row + rr * 8;
                *(float4*)&Bs[kk][b_col] =
                    *(const float4*)(wj + (size_t)(k0 + kk) * H_DIM + n0 + b_col);
            }
            __syncthreads();
            #pragma unroll
            for (int kk = 0; kk < BK; ++kk) {
                float a[8], bb[8];
                *(float4*)&a[0]  = *(const float4*)&As[kk][ty * 8];
                *(float4*)&a[4]  = *(const float4*)&As[kk][ty * 8 + 4];
                *(float4*)&bb[0] = *(const float4*)&Bs[kk][tx * 8];
                *(float4*)&bb[4] = *(const float4*)&Bs[kk][tx * 8 + 4];
                #pragma unroll
                for (int i = 0; i < 8; ++i) {
                    #pragma unroll
                    for (int ll = 0; ll < 8; ++ll)
                        acc[i][ll] = fmaf(a[i], bb[ll], acc[i][ll]);
                }
            }
            __syncthreads();
        }
    }

    float lp[8][3];
    #pragma unroll
    for (int i = 0; i < 8; ++i) { lp[i][0] = 0.f; lp[i][1] = 0.f; lp[i][2] = 0.f; }
    #pragma unroll
    for (int ll = 0; ll < 8; ++ll) {
        int n = n0 + tx * 8 + ll;
        float bias = b1[n];
        float w2m1 = w2[n * 3 + 2];
        float w20  = w2[n * 3 + 1];
        float w2p1 = w2[n * 3 + 0];
        #pragma unroll
        for (int i = 0; i < 8; ++i) {
            float v = acc[i][ll] + bias;
            float g = 0.5f * v * (1.f + erff(v * 0.70710678118654752f));
            lp[i][0] = fmaf(g, w2m1, lp[i][0]);
            lp[i][1] = fmaf(g, w20,  lp[i][1]);
            lp[i][2] = fmaf(g, w2p1, lp[i][2]);
        }
    }
    #pragma unroll
    for (int i = 0; i < 8; ++i) {
        #pragma unroll
        for (int d = 0; d < 3; ++d) {
            float v = lp[i][d];
            v += __shfl_xor(v, 1, 64);
            v += __shfl_xor(v, 2, 64);
            v += __shfl_xor(v, 4, 64);
            v += __shfl_xor(v, 8, 64);
            lp[i][d] = v;
        }
    }
    if (tx == 0) {
        #pragma unroll
        for (int i = 0; i < 8; ++i) {
            ld_lp[0][ty * 8 + i] = lp[i][0];
            ld_lp[1][ty * 8 + i] = lp[i][1];
            ld_lp[2][ty * 8 + i] = lp[i][2];
        }
    }
    __syncthreads();
    float* pout = partials + (size_t)(bm * NBN + bn) * QLEN;
    for (int q = tid; q < QLEN; q += 256) {
        int t = t0 + q - 1;
        if (t >= 0 && t < T_LEN) {
            float v = 0.f;
            if (q >= 1 && q <= BM) v += ld_lp[1][q - 1];
            if (q >= 2)            v += ld_lp[2][q - 2];
            if (q < BM)            v += ld_lp[0][q];
            pout[q] = v;
        }
    }
}

__global__ void k_reduce_logits(const float* __restrict__ partials,
                                const float* __restrict__ b2,
                                float* __restrict__ logits) {
    int M = blockIdx.x * 256 + threadIdx.x;
    if (M >= 4 * T_LEN) return;
    int t = M % T_LEN;
    int bm = M / BM;
    int q = (M % BM) + 1;
    float s = b2[0];
    #pragma unroll
    for (int bn = 0; bn < NBN; ++bn)
        s += partials[(size_t)(bm * NBN + bn) * QLEN + q];
    if ((M % BM) == 0 && t != 0) {
        #pragma unroll
        for (int bn = 0; bn < NBN; ++bn)
            s += partials[(size_t)((bm - 1) * NBN + bn) * QLEN + (QLEN - 1)];
    }
    if ((M % BM) == BM - 1 && t != T_LEN - 1) {
        #pragma unroll
        for (int bn = 0; bn < NBN; ++bn)
            s += partials[(size_t)((bm + 1) * NBN + bn) * QLEN + 0];
    }
    logits[M] = s;
}

// ---------------- launch ----------------
extern "C" void kernel_launch(void* const* d_in, const int* in_sizes, int n_in,
                              void* d_out, int out_size, void* d_ws, size_t ws_size,
                              hipStream_t stream) {
    const float* x  = (const float*)d_in[0];
    const float* w1 = (const float*)d_in[1];
    const float* b1 = (const float*)d_in[2];
    const float* w2 = (const float*)d_in[3];
    const float* b2 = (const float*)d_in[4];
    const float* nw = (const float*)d_in[5];
    float* out = (float*)d_out;

    const size_t XS_ELEMS = (size_t)4 * PADT * D_DIM;          // 33,562,624
    const size_t WS_ELEMS = (size_t)3 * 2 * H_DIM * D_DIM;     // 3,145,728
    const size_t P2_FLOATS = (size_t)NBM2 * NBN2 * QL2;        // 132,096
    const size_t NEED = XS_ELEMS * 2 * sizeof(f16) + WS_ELEMS * sizeof(f16)
                      + (P2_FLOATS + 4 * T_LEN) * sizeof(float);

    if (ws_size >= NEED) {
        f16* xh = (f16*)d_ws;
        f16* xls = xh + XS_ELEMS;
        f16* wsd = xls + XS_ELEMS;
        float* partials = (float*)(wsd + WS_ELEMS);
        float* logits = partials + P2_FLOATS;

        k_split_x<<<(int)(XS_ELEMS / 4 / 256), 256, 0, stream>>>(x, xh, xls);
        k_split_w<<<(3 * H_DIM * D_DIM + 255) / 256, 256, 0, stream>>>(w1, wsd);
        k_conv_gemm_f16<<<NBM2 * NBN2, 512, 0, stream>>>(xh, xls, wsd, b1, w2, partials);
        k_reduce2<<<(4 * T_LEN + 255) / 256, 256, 0, stream>>>(partials, b2, logits);
        k_finalize<<<2048, 256, 0, stream>>>(x, logits, nw, out);
    } else {
        float* w1t      = (float*)d_ws;
        float* partials = w1t + 3 * D_DIM * H_DIM;
        float* logits   = partials + (size_t)NBM * NBN * QLEN;

        k_transpose_w1<<<(3 * D_DIM * H_DIM + 255) / 256, 256, 0, stream>>>(w1, w1t);
        k_conv_gemm<<<dim3(NBM, NBN), 256, 0, stream>>>(x, w1t, b1, w2, partials);
        k_reduce_logits<<<(4 * T_LEN + 255) / 256, 256, 0, stream>>>(partials, b2, logits);
        k_finalize<<<2048, 256, 0, stream>>>(x, logits, nw, out);
    }
}

// Round 10
// 520.343 us; speedup vs baseline: 1.5896x; 1.5896x over previous
//
#include <hip/hip_runtime.h>
#include <hip/hip_bf16.h>
#include <math.h>

#define T_LEN 8192
#define D_DIM 1024
#define H_DIM 512
#define NPATCH 512
#define SEG 16

typedef _Float16 f16;
typedef _Float16 f16x4 __attribute__((ext_vector_type(4)));
typedef _Float16 f16x8 __attribute__((ext_vector_type(8)));
typedef float f32x4 __attribute__((ext_vector_type(4)));

// ---------------- constants ----------------
#define BMR 256            // block rows (t)
#define BNR 128            // block cols (h)
#define NBM2 128           // 32768/256
#define NBN2 4             // 512/128
#define QL2 258            // per-block partial logit slice
#define PADT (T_LEN + 2)   // zero-padded rows per batch
#define RSCALE 2048.0f     // residual scale 2^11 (keeps lo-parts f16-normal)
#define RINV   4.8828125e-4f  // 1/2048

#define ABUFB 32768        // per-buffer LDS: A_hi [256][32] @0, A_lo @16384
#define NSTEP 96           // 3 taps * 32 k-steps
#define BJUMP ((uint32_t)(2 * H_DIM * D_DIM - 992) * 2)   // B byte delta at tap boundary

__device__ __forceinline__ void gll16(const void* g, void* l) {
    __builtin_amdgcn_global_load_lds((const __attribute__((address_space(1))) void*)g,
                                     (__attribute__((address_space(3))) void*)l, 16, 0, 0);
}

// ---------------- K_a: split x (fp32 -> hi f16 + scaled-lo f16, zero-padded rows) ----
__global__ __launch_bounds__(256) void k_split_x(const float* __restrict__ x,
                                                 f16* __restrict__ xh, f16* __restrict__ xls) {
    size_t i4 = (size_t)blockIdx.x * 256 + threadIdx.x;   // unit of 4 elements
    size_t e = i4 * 4;
    int d = (int)(e % D_DIM);
    size_t row = e / D_DIM;
    int pt = (int)(row % PADT);
    int b = (int)(row / PADT);
    f16x4 h, lo;
    if (pt == 0 || pt == PADT - 1) {
        h = (f16x4){0, 0, 0, 0}; lo = (f16x4){0, 0, 0, 0};
    } else {
        float4 v = *(const float4*)(x + ((size_t)b * T_LEN + pt - 1) * D_DIM + d);
        f16 h0 = (f16)v.x, h1 = (f16)v.y, h2 = (f16)v.z, h3 = (f16)v.w;
        h = (f16x4){h0, h1, h2, h3};
        lo = (f16x4){(f16)((v.x - (float)h0) * RSCALE), (f16)((v.y - (float)h1) * RSCALE),
                     (f16)((v.z - (float)h2) * RSCALE), (f16)((v.w - (float)h3) * RSCALE)};
    }
    *(f16x4*)(xh + e) = h;
    *(f16x4*)(xls + e) = lo;
}

// ---------------- K_b: split conv1_w (h,D,3) -> ws[j][hi/lo][o][i] f16 (lo scaled) ----
__global__ void k_split_w(const float* __restrict__ w1, f16* __restrict__ ws) {
    int idx = blockIdx.x * 256 + threadIdx.x;   // over 3*512*1024
    if (idx >= 3 * H_DIM * D_DIM) return;
    int i = idx % D_DIM;
    int o = (idx / D_DIM) % H_DIM;
    int j = idx / (D_DIM * H_DIM);
    float v = w1[((size_t)o * D_DIM + i) * 3 + j];
    f16 h = (f16)v;
    f16 l = (f16)((v - (float)h) * RSCALE);
    ws[((size_t)(j * 2 + 0) * H_DIM + o) * D_DIM + i] = h;
    ws[((size_t)(j * 2 + 1) * H_DIM + o) * D_DIM + i] = l;
}

// ---------------- K_c: MFMA f16-split conv1 + GELU + conv2 partials ----------------
// 8 waves (512 thr). 8-wave workgroups are HW-capped at 256 regs/thread total
// (m69: 8 waves/CU requires <=256); acc = 128 -> arch budget 128. The B-reg
// DOUBLE-buffer (R8/R9) needed ~190 arch -> spilled ~60 regs (WRITE_SIZE 907MB).
// This version: SINGLE 32-reg B set, pipelined at half-set granularity:
//   n01 MFMAs (consume b01) -> load B01(t+1) into b01 -> n23 MFMAs -> load B23(t+1).
// Each half-load has ~1000cyc of MFMA shadow before next-step use (B is L2-resident,
// 1.5MB/XCD slice). Arch ~= A frags 32 + B 32 + addr ~25 + temps -> ~110. No spill.
// A: triple-buffered LDS (3 x 32KB, chunk-XOR swizzle, global_load_lds), uniform
// +64B/step advance. Free-run step; WAIT12 (A(t+1) landed, newer 12 in flight) + BAR.
#define MM3(mi, nj, AH, AL, BH, BL)                                                       \
    ahh[mi][nj] = __builtin_amdgcn_mfma_f32_16x16x32_f16(AH, BH, ahh[mi][nj], 0, 0, 0);   \
    axx[mi][nj] = __builtin_amdgcn_mfma_f32_16x16x32_f16(AH, BL, axx[mi][nj], 0, 0, 0);   \
    axx[mi][nj] = __builtin_amdgcn_mfma_f32_16x16x32_f16(AL, BH, axx[mi][nj], 0, 0, 0);

#define LOADB01() {                                                                       \
    b01[0] = *(const f16x8*)((const char*)wsd + boff[0]);                                 \
    b01[1] = *(const f16x8*)((const char*)wsd + boff[1]);                                 \
    b01[2] = *(const f16x8*)((const char*)wsd + boff[4]);                                 \
    b01[3] = *(const f16x8*)((const char*)wsd + boff[5]); }
#define LOADB23() {                                                                       \
    b23[0] = *(const f16x8*)((const char*)wsd + boff[2]);                                 \
    b23[1] = *(const f16x8*)((const char*)wsd + boff[3]);                                 \
    b23[2] = *(const f16x8*)((const char*)wsd + boff[6]);                                 \
    b23[3] = *(const f16x8*)((const char*)wsd + boff[7]); }
#define ADV01(SN) { uint32_t d_ = ((((SN)) & 31) == 0) ? BJUMP : 64u;                     \
    boff[0] += d_; boff[1] += d_; boff[4] += d_; boff[5] += d_; }
#define ADV23(SN) { uint32_t d_ = ((((SN)) & 31) == 0) ? BJUMP : 64u;                     \
    boff[2] += d_; boff[3] += d_; boff[6] += d_; boff[7] += d_; }

#define WAIT12 asm volatile("s_waitcnt vmcnt(12)" ::: "memory")
#define WAIT8  asm volatile("s_waitcnt vmcnt(8)"  ::: "memory")
#define BAR    __builtin_amdgcn_s_barrier()

__global__ __launch_bounds__(512, 1) void k_conv_gemm_f16(
    const f16* __restrict__ xh, const f16* __restrict__ xls,
    const f16* __restrict__ wsd, const float* __restrict__ b1,
    const float* __restrict__ w2, float* __restrict__ partials)
{
    __shared__ __align__(16) char smem[3 * ABUFB + 6144];   // 104448 B
    const int tid = threadIdx.x;
    const int l = tid & 63, wv = tid >> 6;        // 8 waves
    const int wr = wv >> 1, wc = wv & 1;

    // XCD-bijective swizzle (512 blocks = 8 XCD * 64); 4 bn-blocks sharing an A tile
    // land on one XCD for L2 reuse.
    int bid = blockIdx.x;
    int logical = (bid & 7) * 64 + (bid >> 3);
    const int bm = logical >> 2, bn = logical & 3;
    const int batch = bm >> 5;
    const int lt0 = (bm & 31) * BMR;
    const int n0 = bn * BNR;

    f32x4 ahh[4][4], axx[4][4];
    #pragma unroll
    for (int mi = 0; mi < 4; ++mi)
        #pragma unroll
        for (int nj = 0; nj < 4; ++nj) {
            ahh[mi][nj] = (f32x4){0.f, 0.f, 0.f, 0.f};
            axx[mi][nj] = (f32x4){0.f, 0.f, 0.f, 0.f};
        }

    const int kb = l >> 4, c15 = l & 15;

    // ---- A staging: 4 slots/wave; slot S = wv*4+u; dst = buf + S*1024 ----
    // S<16: A_hi rows [S*16,S*16+16); S>=16: A_lo (offset >=16K = A_lo region).
    const f16* abase = (wv < 4) ? xh : xls;
    uint32_t aoffg[4];
    #pragma unroll
    for (int u = 0; u < 4; ++u) {
        int S = wv * 4 + u;
        int sl = S & 15;
        int m = sl * 16 + (l >> 2);
        int ch = (l & 3) ^ ((m >> 1) & 3);
        aoffg[u] = (uint32_t)(((((uint32_t)batch * PADT + lt0 + m) * D_DIM) + ch * 8) * 2);
    }

    // ---- B direct-load byte offsets (t=0): index p*4+nj, p=0 hi / p=1 lo ----
    uint32_t boff[8];
    #pragma unroll
    for (int p = 0; p < 2; ++p)
        #pragma unroll
        for (int nj = 0; nj < 4; ++nj) {
            int n = n0 + wc * 64 + nj * 16 + c15;
            boff[p * 4 + nj] = (uint32_t)(((((uint32_t)p * H_DIM + n) * D_DIM) + kb * 8) * 2);
        }

    // ---- per-frag LDS byte offsets for A ds_reads (t-invariant) ----
    int aoff_[4];
    #pragma unroll
    for (int mi = 0; mi < 4; ++mi) {
        int m = wr * 64 + mi * 16 + c15;
        aoff_[mi] = m * 64 + ((kb ^ ((m >> 1) & 3)) * 16);
    }

    f16x8 b01[4], b23[4];   // single B set: {hi n0, hi n1, lo n0, lo n1} / n2,n3

    // prologue: A(0)->buf0, A(1)->buf1, B(0) full set; advance B to t=1
    #pragma unroll
    for (int u = 0; u < 4; ++u)
        gll16((const char*)abase + aoffg[u], smem + (wv * 4 + u) * 1024);
    #pragma unroll
    for (int u = 0; u < 4; ++u) {
        gll16((const char*)abase + aoffg[u] + 64, smem + ABUFB + (wv * 4 + u) * 1024);
        aoffg[u] += 128;                       // points at t=2
    }
    LOADB01(); LOADB23();
    ADV01(1); ADV23(1);
    WAIT12;                                    // A(0) landed (A(1)+B(0)=12 newer)
    BAR;

    for (int t = 0; t < NSTEP; ++t) {
        char* buf = smem + (t % 3) * ABUFB;

        // stage A(t+2) into buffer (t+2)%3
        if (t + 2 < NSTEP) {
            char* dsty = smem + ((t + 2) % 3) * ABUFB;
            #pragma unroll
            for (int u = 0; u < 4; ++u) {
                gll16((const char*)abase + aoffg[u], dsty + (wv * 4 + u) * 1024);
                aoffg[u] += 64;
            }
        }

        // A fragment reads for this step
        f16x8 ah0, al0, ah1, al1, ah2, al2, ah3, al3;
        ah0 = *(const f16x8*)(buf + aoff_[0]);  al0 = *(const f16x8*)(buf + 16384 + aoff_[0]);
        ah1 = *(const f16x8*)(buf + aoff_[1]);  al1 = *(const f16x8*)(buf + 16384 + aoff_[1]);
        ah2 = *(const f16x8*)(buf + aoff_[2]);  al2 = *(const f16x8*)(buf + 16384 + aoff_[2]);
        ah3 = *(const f16x8*)(buf + aoff_[3]);  al3 = *(const f16x8*)(buf + 16384 + aoff_[3]);

        // n01 MFMAs (consume b01)
        __builtin_amdgcn_s_setprio(1);
        MM3(0, 0, ah0, al0, b01[0], b01[2]); MM3(0, 1, ah0, al0, b01[1], b01[3]);
        MM3(1, 0, ah1, al1, b01[0], b01[2]); MM3(1, 1, ah1, al1, b01[1], b01[3]);
        MM3(2, 0, ah2, al2, b01[0], b01[2]); MM3(2, 1, ah2, al2, b01[1], b01[3]);
        MM3(3, 0, ah3, al3, b01[0], b01[2]); MM3(3, 1, ah3, al3, b01[1], b01[3]);
        __builtin_amdgcn_s_setprio(0);

        // refill b01 with B01(t+1) (WAR on b01 handled by program order)
        if (t + 1 < NSTEP) { LOADB01(); ADV01(t + 2); }

        // n23 MFMAs (consume b23)
        __builtin_amdgcn_s_setprio(1);
        MM3(0, 2, ah0, al0, b23[0], b23[2]); MM3(0, 3, ah0, al0, b23[1], b23[3]);
        MM3(1, 2, ah1, al1, b23[0], b23[2]); MM3(1, 3, ah1, al1, b23[1], b23[3]);
        MM3(2, 2, ah2, al2, b23[0], b23[2]); MM3(2, 3, ah2, al2, b23[1], b23[3]);
        MM3(3, 2, ah3, al3, b23[0], b23[2]); MM3(3, 3, ah3, al3, b23[1], b23[3]);
        __builtin_amdgcn_s_setprio(0);

        // refill b23 with B23(t+1)
        if (t + 1 < NSTEP) { LOADB23(); ADV23(t + 2); }

        if (t < NSTEP - 2) WAIT12;          // A(t+1) landed; A(t+2)+B(t+1) in flight
        else if (t == NSTEP - 2) WAIT8;     // only B(95)'s 8 newest outstanding
        BAR;
    }

    // epilogue: combine hh + cross*2^-11, bias + exact GELU + conv2 tap fold
    float* lp_lds = (float*)(smem + 3 * ABUFB);   // [wc][d][m] = [2][3][256]
    #pragma unroll
    for (int mi = 0; mi < 4; ++mi) {
        float lp[4][3] = {};
        #pragma unroll
        for (int nj = 0; nj < 4; ++nj) {
            int n = n0 + wc * 64 + nj * 16 + c15;
            float bias = b1[n];
            float w2m1 = w2[n * 3 + 2];   // hcv[t] -> logits[t-1]
            float w20  = w2[n * 3 + 1];
            float w2p1 = w2[n * 3 + 0];
            #pragma unroll
            for (int r = 0; r < 4; ++r) {
                float v = ahh[mi][nj][r] + axx[mi][nj][r] * RINV + bias;
                float g = 0.5f * v * (1.f + erff(v * 0.70710678118654752f));
                lp[r][0] = fmaf(g, w2m1, lp[r][0]);
                lp[r][1] = fmaf(g, w20,  lp[r][1]);
                lp[r][2] = fmaf(g, w2p1, lp[r][2]);
            }
        }
        #pragma unroll
        for (int r = 0; r < 4; ++r)
            #pragma unroll
            for (int d = 0; d < 3; ++d) {
                float v = lp[r][d];
                v += __shfl_xor(v, 1, 64);
                v += __shfl_xor(v, 2, 64);
                v += __shfl_xor(v, 4, 64);
                v += __shfl_xor(v, 8, 64);
                lp[r][d] = v;
            }
        if (c15 == 0) {
            int m = wr * 64 + mi * 16 + kb * 4;
            #pragma unroll
            for (int r = 0; r < 4; ++r)
                #pragma unroll
                for (int d = 0; d < 3; ++d)
                    lp_lds[(wc * 3 + d) * 256 + m + r] = lp[r][d];
        }
    }
    __syncthreads();

    float* pout = partials + (size_t)(bm * NBN2 + bn) * QL2;
    for (int q = tid; q < QL2; q += 512) {
        int tloc = lt0 + q - 1;
        if (tloc >= 0 && tloc < T_LEN) {
            float v = 0.f;
            #pragma unroll
            for (int w2c = 0; w2c < 2; ++w2c) {
                if (q >= 1 && q <= 256) v += lp_lds[(w2c * 3 + 1) * 256 + q - 1];
                if (q >= 2)             v += lp_lds[(w2c * 3 + 2) * 256 + q - 2];
                if (q < 256)            v += lp_lds[(w2c * 3 + 0) * 256 + q];
            }
            pout[q] = v;
        }
    }
}

// ---------------- K_d: deterministic logit reduction (256-row blocks) ----------------
__global__ void k_reduce2(const float* __restrict__ partials,
                          const float* __restrict__ b2, float* __restrict__ logits) {
    int M = blockIdx.x * 256 + threadIdx.x;
    if (M >= 4 * T_LEN) return;
    int t = M & (T_LEN - 1);
    int bm = M >> 8;
    int mq = M & 255;
    int q = mq + 1;
    float s = b2[0];
    #pragma unroll
    for (int bn = 0; bn < NBN2; ++bn)
        s += partials[(size_t)(bm * NBN2 + bn) * QL2 + q];
    if (mq == 0 && t != 0) {
        #pragma unroll
        for (int bn = 0; bn < NBN2; ++bn)
            s += partials[(size_t)((bm - 1) * NBN2 + bn) * QL2 + (QL2 - 1)];
    }
    if (mq == 255 && t != T_LEN - 1) {
        #pragma unroll
        for (int bn = 0; bn < NBN2; ++bn)
            s += partials[(size_t)((bm + 1) * NBN2 + bn) * QL2 + 0];
    }
    logits[M] = s;
}

// ---------------- K3: softmax/centroid/entropy + gather + RMSNorm ----------------
__global__ __launch_bounds__(256) void k_finalize(
    const float* __restrict__ x, const float* __restrict__ logits,
    const float* __restrict__ norm_w, float* __restrict__ out)
{
    int blk = blockIdx.x;            // 0..2047
    int b = blk >> 9, p = blk & 511;
    const float* lg = logits + b * T_LEN + p * SEG;

    float l[SEG];
    #pragma unroll
    for (int i = 0; i < SEG; ++i) l[i] = lg[i];
    float mx = l[0];
    #pragma unroll
    for (int i = 1; i < SEG; ++i) mx = fmaxf(mx, l[i]);
    float w[SEG];
    float s = 0.f;
    #pragma unroll
    for (int i = 0; i < SEG; ++i) { w[i] = expf(l[i] - mx); s += w[i]; }
    float inv = 1.f / s;
    float boundary = 0.f, ent = 0.f;
    #pragma unroll
    for (int i = 0; i < SEG; ++i) {
        float wi = w[i] * inv;
        boundary += wi * (float)(p * SEG + i);
        ent -= wi * logf(fmaxf(wi, 1e-8f));
    }
    ent *= 0.36067376022224085f;     // 1 / log(16)

    int idx = (int)boundary;
    idx = min(max(idx, 0), T_LEN - 1);

    const float* row = x + ((size_t)b * T_LEN + idx) * D_DIM;
    int tid = threadIdx.x;
    float v[4];
    float ss = 0.f;
    #pragma unroll
    for (int r = 0; r < 4; ++r) {
        int c = tid + r * 256;
        v[r] = row[c];
        ss = fmaf(v[r], v[r], ss);
    }
    #pragma unroll
    for (int off = 32; off > 0; off >>= 1) ss += __shfl_down(ss, off, 64);
    __shared__ float sred[4];
    if ((tid & 63) == 0) sred[tid >> 6] = ss;
    __syncthreads();
    float tot = sred[0] + sred[1] + sred[2] + sred[3];
    float rms = rsqrtf(tot * (1.f / 1024.f) + 1e-6f);

    float* o0 = out + ((size_t)b * NPATCH + p) * D_DIM;
    #pragma unroll
    for (int r = 0; r < 4; ++r) {
        int c = tid + r * 256;
        o0[c] = v[r] * rms * norm_w[c];
    }
    if (tid == 0)
        out[(size_t)4 * NPATCH * D_DIM + b * NPATCH + p] = ent;
}

// ==================== fallback (round-1 fp32 path, known-passing) ====================
#define BM 128
#define BN 128
#define BK 16
#define NBM (4 * T_LEN / BM)
#define NBN (H_DIM / BN)
#define QLEN 130

__global__ void k_transpose_w1(const float* __restrict__ w1, float* __restrict__ w1t) {
    int idx = blockIdx.x * 256 + threadIdx.x;
    if (idx >= 3 * D_DIM * H_DIM) return;
    int o = idx % H_DIM;
    int i = (idx / H_DIM) % D_DIM;
    int j = idx / (H_DIM * D_DIM);
    w1t[idx] = w1[(o * D_DIM + i) * 3 + j];
}

__global__ __launch_bounds__(256) void k_conv_gemm(
    const float* __restrict__ x, const float* __restrict__ w1t,
    const float* __restrict__ b1, const float* __restrict__ w2,
    float* __restrict__ partials)
{
    __shared__ float As[BK][BM + 4];
    __shared__ float Bs[BK][BN];
    __shared__ float ld_lp[3][BM];

    const int bm = blockIdx.x, bn = blockIdx.y;
    const int m0 = bm * BM;
    const int batch = m0 / T_LEN;
    const int t0 = m0 % T_LEN;
    const int n0 = bn * BN;
    const int tid = threadIdx.x;
    const int tx = tid & 15, ty = tid >> 4;

    float acc[8][8] = {};

    const int a_col = (tid & 3) * 4;
    const int a_row = tid >> 2;
    const int b_row = tid >> 5;
    const int b_col = (tid & 31) * 4;

    const float* xb = x + (size_t)batch * T_LEN * D_DIM;

    for (int j = 0; j < 3; ++j) {
        const float* wj = w1t + (size_t)j * D_DIM * H_DIM;
        const int tshift = j - 1;
        for (int k0 = 0; k0 < D_DIM; k0 += BK) {
            #pragma unroll
            for (int rr = 0; rr < 2; ++rr) {
                int m = a_row + rr * 64;
                int tt = t0 + m + tshift;
                float4 v = make_float4(0.f, 0.f, 0.f, 0.f);
                if (tt >= 0 && tt < T_LEN)
                    v = *(const float4*)(xb + (size_t)tt * D_DIM + k0 + a_col);
                As[a_col + 0][m] = v.x; As[a_col + 1][m] = v.y;
                As[a_col + 2][m] = v.z; As[a_col + 3][m] = v.w;
            }
            #pragma unroll
            for (int rr = 0; rr < 2; ++rr) {
                int kk = b_row + rr * 8;
                *(float4*)&Bs[kk][b_col] =
                    *(const float4*)(wj + (size_t)(k0 + kk) * H_DIM + n0 + b_col);
            }
            __syncthreads();
            #pragma unroll
            for (int kk = 0; kk < BK; ++kk) {
                float a[8], bb[8];
                *(float4*)&a[0]  = *(const float4*)&As[kk][ty * 8];
                *(float4*)&a[4]  = *(const float4*)&As[kk][ty * 8 + 4];
                *(float4*)&bb[0] = *(const float4*)&Bs[kk][tx * 8];
                *(float4*)&bb[4] = *(const float4*)&Bs[kk][tx * 8 + 4];
                #pragma unroll
                for (int i = 0; i < 8; ++i) {
                    #pragma unroll
                    for (int ll = 0; ll < 8; ++ll)
                        acc[i][ll] = fmaf(a[i], bb[ll], acc[i][ll]);
                }
            }
            __syncthreads();
        }
    }

    float lp[8][3];
    #pragma unroll
    for (int i = 0; i < 8; ++i) { lp[i][0] = 0.f; lp[i][1] = 0.f; lp[i][2] = 0.f; }
    #pragma unroll
    for (int ll = 0; ll < 8; ++ll) {
        int n = n0 + tx * 8 + ll;
        float bias = b1[n];
        float w2m1 = w2[n * 3 + 2];
        float w20  = w2[n * 3 + 1];
        float w2p1 = w2[n * 3 + 0];
        #pragma unroll
        for (int i = 0; i < 8; ++i) {
            float v = acc[i][ll] + bias;
            float g = 0.5f * v * (1.f + erff(v * 0.70710678118654752f));
            lp[i][0] = fmaf(g, w2m1, lp[i][0]);
            lp[i][1] = fmaf(g, w20,  lp[i][1]);
            lp[i][2] = fmaf(g, w2p1, lp[i][2]);
        }
    }
    #pragma unroll
    for (int i = 0; i < 8; ++i) {
        #pragma unroll
        for (int d = 0; d < 3; ++d) {
            float v = lp[i][d];
            v += __shfl_xor(v, 1, 64);
            v += __shfl_xor(v, 2, 64);
            v += __shfl_xor(v, 4, 64);
            v += __shfl_xor(v, 8, 64);
            lp[i][d] = v;
        }
    }
    if (tx == 0) {
        #pragma unroll
        for (int i = 0; i < 8; ++i) {
            ld_lp[0][ty * 8 + i] = lp[i][0];
            ld_lp[1][ty * 8 + i] = lp[i][1];
            ld_lp[2][ty * 8 + i] = lp[i][2];
        }
    }
    __syncthreads();
    float* pout = partials + (size_t)(bm * NBN + bn) * QLEN;
    for (int q = tid; q < QLEN; q += 256) {
        int t = t0 + q - 1;
        if (t >= 0 && t < T_LEN) {
            float v = 0.f;
            if (q >= 1 && q <= BM) v += ld_lp[1][q - 1];
            if (q >= 2)            v += ld_lp[2][q - 2];
            if (q < BM)            v += ld_lp[0][q];
            pout[q] = v;
        }
    }
}

__global__ void k_reduce_logits(const float* __restrict__ partials,
                                const float* __restrict__ b2,
                                float* __restrict__ logits) {
    int M = blockIdx.x * 256 + threadIdx.x;
    if (M >= 4 * T_LEN) return;
    int t = M % T_LEN;
    int bm = M / BM;
    int q = (M % BM) + 1;
    float s = b2[0];
    #pragma unroll
    for (int bn = 0; bn < NBN; ++bn)
        s += partials[(size_t)(bm * NBN + bn) * QLEN + q];
    if ((M % BM) == 0 && t != 0) {
        #pragma unroll
        for (int bn = 0; bn < NBN; ++bn)
            s += partials[(size_t)((bm - 1) * NBN + bn) * QLEN + (QLEN - 1)];
    }
    if ((M % BM) == BM - 1 && t != T_LEN - 1) {
        #pragma unroll
        for (int bn = 0; bn < NBN; ++bn)
            s += partials[(size_t)((bm + 1) * NBN + bn) * QLEN + 0];
    }
    logits[M] = s;
}

// ---------------- launch ----------------
extern "C" void kernel_launch(void* const* d_in, const int* in_sizes, int n_in,
                              void* d_out, int out_size, void* d_ws, size_t ws_size,
                              hipStream_t stream) {
    const float* x  = (const float*)d_in[0];
    const float* w1 = (const float*)d_in[1];
    const float* b1 = (const float*)d_in[2];
    const float* w2 = (const float*)d_in[3];
    const float* b2 = (const float*)d_in[4];
    const float* nw = (const float*)d_in[5];
    float* out = (float*)d_out;

    const size_t XS_ELEMS = (size_t)4 * PADT * D_DIM;          // 33,562,624
    const size_t WS_ELEMS = (size_t)3 * 2 * H_DIM * D_DIM;     // 3,145,728
    const size_t P2_FLOATS = (size_t)NBM2 * NBN2 * QL2;        // 132,096
    const size_t NEED = XS_ELEMS * 2 * sizeof(f16) + WS_ELEMS * sizeof(f16)
                      + (P2_FLOATS + 4 * T_LEN) * sizeof(float);

    if (ws_size >= NEED) {
        f16* xh = (f16*)d_ws;
        f16* xls = xh + XS_ELEMS;
        f16* wsd = xls + XS_ELEMS;
        float* partials = (float*)(wsd + WS_ELEMS);
        float* logits = partials + P2_FLOATS;

        k_split_x<<<(int)(XS_ELEMS / 4 / 256), 256, 0, stream>>>(x, xh, xls);
        k_split_w<<<(3 * H_DIM * D_DIM + 255) / 256, 256, 0, stream>>>(w1, wsd);
        k_conv_gemm_f16<<<NBM2 * NBN2, 512, 0, stream>>>(xh, xls, wsd, b1, w2, partials);
        k_reduce2<<<(4 * T_LEN + 255) / 256, 256, 0, stream>>>(partials, b2, logits);
        k_finalize<<<2048, 256, 0, stream>>>(x, logits, nw, out);
    } else {
        float* w1t      = (float*)d_ws;
        float* partials = w1t + 3 * D_DIM * H_DIM;
        float* logits   = partials + (size_t)NBM * NBN * QLEN;

        k_transpose_w1<<<(3 * D_DIM * H_DIM + 255) / 256, 256, 0, stream>>>(w1, w1t);
        k_conv_gemm<<<dim3(NBM, NBN), 256, 0, stream>>>(x, w1t, b1, w2, partials);
        k_reduce_logits<<<(4 * T_LEN + 255) / 256, 256, 0, stream>>>(partials, b2, logits);
        k_finalize<<<2048, 256, 0, stream>>>(x, logits, nw, out);
    }
}

// Round 11
// 336.846 us; speedup vs baseline: 2.4555x; 1.5448x over previous
//
#include <hip/hip_runtime.h>
#include <hip/hip_bf16.h>
#include <math.h>

#define T_LEN 8192
#define D_DIM 1024
#define H_DIM 512
#define NPATCH 512
#define SEG 16

typedef _Float16 f16;
typedef _Float16 f16x4 __attribute__((ext_vector_type(4)));
typedef _Float16 f16x8 __attribute__((ext_vector_type(8)));
typedef float f32x4 __attribute__((ext_vector_type(4)));

// ---------------- constants ----------------
#define BMR 256            // block rows (t)
#define BNR 128            // block cols (h)
#define NBM2 128           // 32768/256
#define NBN2 4             // 512/128
#define QL2 258            // per-block partial logit slice
#define PADT (T_LEN + 2)   // zero-padded rows per batch
#define RSCALE 2048.0f     // residual scale 2^11 (keeps lo-parts f16-normal)
#define RINV   4.8828125e-4f  // 1/2048

#define BUFB 49152         // bytes per LDS K-step buffer (A_hi 16K, A_lo 16K, B_hi 8K, B_lo 8K)
#define NSTEP 96           // 3 taps * 32 k-steps

__device__ __forceinline__ void gll16(const void* g, void* l) {
    __builtin_amdgcn_global_load_lds((const __attribute__((address_space(1))) void*)g,
                                     (__attribute__((address_space(3))) void*)l, 16, 0, 0);
}

// ---------------- K_a: split x (fp32 -> hi f16 + scaled-lo f16, zero-padded rows) ----
__global__ __launch_bounds__(256) void k_split_x(const float* __restrict__ x,
                                                 f16* __restrict__ xh, f16* __restrict__ xls) {
    size_t i4 = (size_t)blockIdx.x * 256 + threadIdx.x;   // unit of 4 elements
    size_t e = i4 * 4;
    int d = (int)(e % D_DIM);
    size_t row = e / D_DIM;
    int pt = (int)(row % PADT);
    int b = (int)(row / PADT);
    f16x4 h, lo;
    if (pt == 0 || pt == PADT - 1) {
        h = (f16x4){0, 0, 0, 0}; lo = (f16x4){0, 0, 0, 0};
    } else {
        float4 v = *(const float4*)(x + ((size_t)b * T_LEN + pt - 1) * D_DIM + d);
        f16 h0 = (f16)v.x, h1 = (f16)v.y, h2 = (f16)v.z, h3 = (f16)v.w;
        h = (f16x4){h0, h1, h2, h3};
        lo = (f16x4){(f16)((v.x - (float)h0) * RSCALE), (f16)((v.y - (float)h1) * RSCALE),
                     (f16)((v.z - (float)h2) * RSCALE), (f16)((v.w - (float)h3) * RSCALE)};
    }
    *(f16x4*)(xh + e) = h;
    *(f16x4*)(xls + e) = lo;
}

// ---------------- K_b: split conv1_w (h,D,3) -> ws[j][hi/lo][o][i] f16 (lo scaled) ----
__global__ void k_split_w(const float* __restrict__ w1, f16* __restrict__ ws) {
    int idx = blockIdx.x * 256 + threadIdx.x;   // over 3*512*1024
    if (idx >= 3 * H_DIM * D_DIM) return;
    int i = idx % D_DIM;
    int o = (idx / D_DIM) % H_DIM;
    int j = idx / (D_DIM * H_DIM);
    float v = w1[((size_t)o * D_DIM + i) * 3 + j];
    f16 h = (f16)v;
    f16 l = (f16)((v - (float)h) * RSCALE);
    ws[((size_t)(j * 2 + 0) * H_DIM + o) * D_DIM + i] = h;
    ws[((size_t)(j * 2 + 1) * H_DIM + o) * D_DIM + i] = l;
}

// ---------------- K_c: MFMA f16-split conv1 + GELU + conv2 partials ----------------
// 8 waves (512 thr). Block 256x128, wave tile 64x64 (wr in [0,4), wc in [0,2)).
// Triple-buffered LDS (3 x 48KB) + lp 6KB = 150KB -> 1 block/CU.
// Per K-step (BK=32 f16): 16 ds_read_b128 + 48 MFMA + 6 stage-issues, FREE-RUN
// (no intra-step barriers; compiler interleaves, waves drift into complementary
// roles). ONE barrier per step after counted vmcnt(6). Buffer layout (per buf):
// A_hi [256][32] @0, A_lo @16384, B_hi [128][32] @32768, B_lo @40960.
// Row = 64B = 4 chunks of 16B; stored chunk c' holds k-chunk c' ^ ((row>>1)&3).
// Register budget: arch 116 + acc 128 = 244 of the 256-reg 8-wave cap. This is
// the measured optimum (290us, MfmaUtil 50.7%); all deeper-pipelined variants
// (B-reg double buffer, frag prefetch, 2-block dbuf, 32x32 shape) regressed.
#define MM3(mi, nj, AH, AL, BH, BL)                                                       \
    ahh[mi][nj] = __builtin_amdgcn_mfma_f32_16x16x32_f16(AH, BH, ahh[mi][nj], 0, 0, 0);   \
    axx[mi][nj] = __builtin_amdgcn_mfma_f32_16x16x32_f16(AH, BL, axx[mi][nj], 0, 0, 0);   \
    axx[mi][nj] = __builtin_amdgcn_mfma_f32_16x16x32_f16(AL, BH, axx[mi][nj], 0, 0, 0);

__global__ __launch_bounds__(512, 2) void k_conv_gemm_f16(
    const f16* __restrict__ xh, const f16* __restrict__ xls,
    const f16* __restrict__ wsd, const float* __restrict__ b1,
    const float* __restrict__ w2, float* __restrict__ partials)
{
    __shared__ __align__(16) char smem[3 * BUFB + 6144];
    const int tid = threadIdx.x;
    const int l = tid & 63, wv = tid >> 6;        // 8 waves
    const int wr = wv >> 1, wc = wv & 1;

    // XCD-bijective swizzle (512 blocks = 8 XCD * 64); 4 bn-blocks sharing an A tile
    // land on one XCD for L2 reuse.
    int bid = blockIdx.x;
    int logical = (bid & 7) * 64 + (bid >> 3);
    const int bm = logical >> 2, bn = logical & 3;
    const int batch = bm >> 5;
    const int lt0 = (bm & 31) * BMR;
    const int n0 = bn * BNR;

    f32x4 ahh[4][4], axx[4][4];
    #pragma unroll
    for (int mi = 0; mi < 4; ++mi)
        #pragma unroll
        for (int nj = 0; nj < 4; ++nj) {
            ahh[mi][nj] = (f32x4){0.f, 0.f, 0.f, 0.f};
            axx[mi][nj] = (f32x4){0.f, 0.f, 0.f, 0.f};
        }

    const int kb = l >> 4, c15 = l & 15;

    // per-slot staging bases (j=0, k0=0); addr(t) = base0 + (t>>5)*jstr + (t&31)*32
    const f16* base0[6];
    int jstr[6];
    #pragma unroll
    for (int u = 0; u < 6; ++u) {
        int s = wv * 6 + u;
        if (s < 32) {                      // A slots: 0-15 hi, 16-31 lo
            int which = s >> 4, sl = s & 15;
            int m = sl * 16 + (l >> 2);
            int ch = (l & 3) ^ ((m >> 1) & 3);
            base0[u] = (which ? xls : xh) + ((size_t)batch * PADT + lt0) * D_DIM
                       + (size_t)m * D_DIM + ch * 8;
            jstr[u] = D_DIM;
        } else {                           // B slots: 32-39 hi, 40-47 lo
            int s2 = s - 32, which = s2 >> 3, sl = s2 & 7;
            int n = sl * 16 + (l >> 2);
            int ch = (l & 3) ^ ((n >> 1) & 3);
            base0[u] = wsd + ((size_t)which * H_DIM + n0) * D_DIM + (size_t)n * D_DIM + ch * 8;
            jstr[u] = 2 * H_DIM * D_DIM;
        }
    }

    // per-frag LDS byte offsets (t-invariant)
    int aoff_[4], boff_[4];
    #pragma unroll
    for (int mi = 0; mi < 4; ++mi) {
        int m = wr * 64 + mi * 16 + c15;
        aoff_[mi] = m * 64 + ((kb ^ ((m >> 1) & 3)) * 16);
    }
    #pragma unroll
    for (int nj = 0; nj < 4; ++nj) {
        int n = wc * 64 + nj * 16 + c15;
        boff_[nj] = n * 64 + ((kb ^ ((n >> 1) & 3)) * 16);
    }

    // prologue: stage steps 0 (buf0) and 1 (buf1); wait step0's own 6 loads
    #pragma unroll
    for (int u = 0; u < 6; ++u)
        gll16(base0[u], smem + (wv * 6 + u) * 1024);
    #pragma unroll
    for (int u = 0; u < 6; ++u)
        gll16(base0[u] + 32, smem + BUFB + (wv * 6 + u) * 1024);
    asm volatile("s_waitcnt vmcnt(6)" ::: "memory");
    __builtin_amdgcn_s_barrier();

    for (int t = 0; t < NSTEP; ++t) {
        char* buf = smem + (t % 3) * BUFB;
        f16x8 ah0, al0, ah1, al1, ah2, al2, ah3, al3;
        f16x8 bh0, bl0, bh1, bl1, bh2, bl2, bh3, bl3;

        // all fragment reads for this step (compiler schedules / interleaves)
        ah0 = *(const f16x8*)(buf + aoff_[0]);          al0 = *(const f16x8*)(buf + 16384 + aoff_[0]);
        ah1 = *(const f16x8*)(buf + aoff_[1]);          al1 = *(const f16x8*)(buf + 16384 + aoff_[1]);
        ah2 = *(const f16x8*)(buf + aoff_[2]);          al2 = *(const f16x8*)(buf + 16384 + aoff_[2]);
        ah3 = *(const f16x8*)(buf + aoff_[3]);          al3 = *(const f16x8*)(buf + 16384 + aoff_[3]);
        bh0 = *(const f16x8*)(buf + 32768 + boff_[0]);  bl0 = *(const f16x8*)(buf + 40960 + boff_[0]);
        bh1 = *(const f16x8*)(buf + 32768 + boff_[1]);  bl1 = *(const f16x8*)(buf + 40960 + boff_[1]);
        bh2 = *(const f16x8*)(buf + 32768 + boff_[2]);  bl2 = *(const f16x8*)(buf + 40960 + boff_[2]);
        bh3 = *(const f16x8*)(buf + 32768 + boff_[3]);  bl3 = *(const f16x8*)(buf + 40960 + boff_[3]);

        // stage all 6 slots for step t+2 (triple buffer; lands before t+2's barrier)
        {
            int sv = t + 2;
            if (sv < NSTEP) {
                char* dsty = smem + (sv % 3) * BUFB;
                int jj = sv >> 5, ko = (sv & 31) * 32;
                #pragma unroll
                for (int u = 0; u < 6; ++u)
                    gll16(base0[u] + (size_t)jj * jstr[u] + ko, dsty + (wv * 6 + u) * 1024);
            }
        }

        __builtin_amdgcn_s_setprio(1);
        MM3(0, 0, ah0, al0, bh0, bl0); MM3(0, 1, ah0, al0, bh1, bl1);
        MM3(1, 0, ah1, al1, bh0, bl0); MM3(1, 1, ah1, al1, bh1, bl1);
        MM3(2, 0, ah2, al2, bh0, bl0); MM3(2, 1, ah2, al2, bh1, bl1);
        MM3(3, 0, ah3, al3, bh0, bl0); MM3(3, 1, ah3, al3, bh1, bl1);
        MM3(2, 2, ah2, al2, bh2, bl2); MM3(2, 3, ah2, al2, bh3, bl3);
        MM3(3, 2, ah3, al3, bh2, bl2); MM3(3, 3, ah3, al3, bh3, bl3);
        MM3(0, 2, ah0, al0, bh2, bl2); MM3(0, 3, ah0, al0, bh3, bl3);
        MM3(1, 2, ah1, al1, bh2, bl2); MM3(1, 3, ah1, al1, bh3, bl3);
        __builtin_amdgcn_s_setprio(0);

        if (t < NSTEP - 2)
            asm volatile("s_waitcnt vmcnt(6)" ::: "memory");   // (t+1)'s loads done, (t+2)'s in flight
        else if (t == NSTEP - 2)
            asm volatile("s_waitcnt vmcnt(0)" ::: "memory");   // last staged step
        __builtin_amdgcn_s_barrier();
    }

    // epilogue: combine hh + cross*2^-11, bias + exact GELU + conv2 tap fold
    float* lp_lds = (float*)(smem + 3 * BUFB);   // [wc][d][m] = [2][3][256]
    #pragma unroll
    for (int mi = 0; mi < 4; ++mi) {
        float lp[4][3] = {};
        #pragma unroll
        for (int nj = 0; nj < 4; ++nj) {
            int n = n0 + wc * 64 + nj * 16 + c15;
            float bias = b1[n];
            float w2m1 = w2[n * 3 + 2];   // hcv[t] -> logits[t-1]
            float w20  = w2[n * 3 + 1];
            float w2p1 = w2[n * 3 + 0];
            #pragma unroll
            for (int r = 0; r < 4; ++r) {
                float v = ahh[mi][nj][r] + axx[mi][nj][r] * RINV + bias;
                float g = 0.5f * v * (1.f + erff(v * 0.70710678118654752f));
                lp[r][0] = fmaf(g, w2m1, lp[r][0]);
                lp[r][1] = fmaf(g, w20,  lp[r][1]);
                lp[r][2] = fmaf(g, w2p1, lp[r][2]);
            }
        }
        #pragma unroll
        for (int r = 0; r < 4; ++r)
            #pragma unroll
            for (int d = 0; d < 3; ++d) {
                float v = lp[r][d];
                v += __shfl_xor(v, 1, 64);
                v += __shfl_xor(v, 2, 64);
                v += __shfl_xor(v, 4, 64);
                v += __shfl_xor(v, 8, 64);
                lp[r][d] = v;
            }
        if (c15 == 0) {
            int m = wr * 64 + mi * 16 + kb * 4;
            #pragma unroll
            for (int r = 0; r < 4; ++r)
                #pragma unroll
                for (int d = 0; d < 3; ++d)
                    lp_lds[(wc * 3 + d) * 256 + m + r] = lp[r][d];
        }
    }
    __syncthreads();

    float* pout = partials + (size_t)(bm * NBN2 + bn) * QL2;
    for (int q = tid; q < QL2; q += 512) {
        int tloc = lt0 + q - 1;
        if (tloc >= 0 && tloc < T_LEN) {
            float v = 0.f;
            #pragma unroll
            for (int w2c = 0; w2c < 2; ++w2c) {
                if (q >= 1 && q <= 256) v += lp_lds[(w2c * 3 + 1) * 256 + q - 1];
                if (q >= 2)             v += lp_lds[(w2c * 3 + 2) * 256 + q - 2];
                if (q < 256)            v += lp_lds[(w2c * 3 + 0) * 256 + q];
            }
            pout[q] = v;
        }
    }
}

// ---------------- K_d: deterministic logit reduction (256-row blocks) ----------------
__global__ void k_reduce2(const float* __restrict__ partials,
                          const float* __restrict__ b2, float* __restrict__ logits) {
    int M = blockIdx.x * 256 + threadIdx.x;
    if (M >= 4 * T_LEN) return;
    int t = M & (T_LEN - 1);
    int bm = M >> 8;
    int mq = M & 255;
    int q = mq + 1;
    float s = b2[0];
    #pragma unroll
    for (int bn = 0; bn < NBN2; ++bn)
        s += partials[(size_t)(bm * NBN2 + bn) * QL2 + q];
    if (mq == 0 && t != 0) {
        #pragma unroll
        for (int bn = 0; bn < NBN2; ++bn)
            s += partials[(size_t)((bm - 1) * NBN2 + bn) * QL2 + (QL2 - 1)];
    }
    if (mq == 255 && t != T_LEN - 1) {
        #pragma unroll
        for (int bn = 0; bn < NBN2; ++bn)
            s += partials[(size_t)((bm + 1) * NBN2 + bn) * QL2 + 0];
    }
    logits[M] = s;
}

// ---------------- K3: softmax/centroid/entropy + gather + RMSNorm ----------------
__global__ __launch_bounds__(256) void k_finalize(
    const float* __restrict__ x, const float* __restrict__ logits,
    const float* __restrict__ norm_w, float* __restrict__ out)
{
    int blk = blockIdx.x;            // 0..2047
    int b = blk >> 9, p = blk & 511;
    const float* lg = logits + b * T_LEN + p * SEG;

    float l[SEG];
    #pragma unroll
    for (int i = 0; i < SEG; ++i) l[i] = lg[i];
    float mx = l[0];
    #pragma unroll
    for (int i = 1; i < SEG; ++i) mx = fmaxf(mx, l[i]);
    float w[SEG];
    float s = 0.f;
    #pragma unroll
    for (int i = 0; i < SEG; ++i) { w[i] = expf(l[i] - mx); s += w[i]; }
    float inv = 1.f / s;
    float boundary = 0.f, ent = 0.f;
    #pragma unroll
    for (int i = 0; i < SEG; ++i) {
        float wi = w[i] * inv;
        boundary += wi * (float)(p * SEG + i);
        ent -= wi * logf(fmaxf(wi, 1e-8f));
    }
    ent *= 0.36067376022224085f;     // 1 / log(16)

    int idx = (int)boundary;
    idx = min(max(idx, 0), T_LEN - 1);

    const float* row = x + ((size_t)b * T_LEN + idx) * D_DIM;
    int tid = threadIdx.x;
    float v[4];
    float ss = 0.f;
    #pragma unroll
    for (int r = 0; r < 4; ++r) {
        int c = tid + r * 256;
        v[r] = row[c];
        ss = fmaf(v[r], v[r], ss);
    }
    #pragma unroll
    for (int off = 32; off > 0; off >>= 1) ss += __shfl_down(ss, off, 64);
    __shared__ float sred[4];
    if ((tid & 63) == 0) sred[tid >> 6] = ss;
    __syncthreads();
    float tot = sred[0] + sred[1] + sred[2] + sred[3];
    float rms = rsqrtf(tot * (1.f / 1024.f) + 1e-6f);

    float* o0 = out + ((size_t)b * NPATCH + p) * D_DIM;
    #pragma unroll
    for (int r = 0; r < 4; ++r) {
        int c = tid + r * 256;
        o0[c] = v[r] * rms * norm_w[c];
    }
    if (tid == 0)
        out[(size_t)4 * NPATCH * D_DIM + b * NPATCH + p] = ent;
}

// ==================== fallback (round-1 fp32 path, known-passing) ====================
#define BM 128
#define BN 128
#define BK 16
#define NBM (4 * T_LEN / BM)
#define NBN (H_DIM / BN)
#define QLEN 130

__global__ void k_transpose_w1(const float* __restrict__ w1, float* __restrict__ w1t) {
    int idx = blockIdx.x * 256 + threadIdx.x;
    if (idx >= 3 * D_DIM * H_DIM) return;
    int o = idx % H_DIM;
    int i = (idx / H_DIM) % D_DIM;
    int j = idx / (H_DIM * D_DIM);
    w1t[idx] = w1[(o * D_DIM + i) * 3 + j];
}

__global__ __launch_bounds__(256) void k_conv_gemm(
    const float* __restrict__ x, const float* __restrict__ w1t,
    const float* __restrict__ b1, const float* __restrict__ w2,
    float* __restrict__ partials)
{
    __shared__ float As[BK][BM + 4];
    __shared__ float Bs[BK][BN];
    __shared__ float ld_lp[3][BM];

    const int bm = blockIdx.x, bn = blockIdx.y;
    const int m0 = bm * BM;
    const int batch = m0 / T_LEN;
    const int t0 = m0 % T_LEN;
    const int n0 = bn * BN;
    const int tid = threadIdx.x;
    const int tx = tid & 15, ty = tid >> 4;

    float acc[8][8] = {};

    const int a_col = (tid & 3) * 4;
    const int a_row = tid >> 2;
    const int b_row = tid >> 5;
    const int b_col = (tid & 31) * 4;

    const float* xb = x + (size_t)batch * T_LEN * D_DIM;

    for (int j = 0; j < 3; ++j) {
        const float* wj = w1t + (size_t)j * D_DIM * H_DIM;
        const int tshift = j - 1;
        for (int k0 = 0; k0 < D_DIM; k0 += BK) {
            #pragma unroll
            for (int rr = 0; rr < 2; ++rr) {
                int m = a_row + rr * 64;
                int tt = t0 + m + tshift;
                float4 v = make_float4(0.f, 0.f, 0.f, 0.f);
                if (tt >= 0 && tt < T_LEN)
                    v = *(const float4*)(xb + (size_t)tt * D_DIM + k0 + a_col);
                As[a_col + 0][m] = v.x; As[a_col + 1][m] = v.y;
                As[a_col + 2][m] = v.z; As[a_col + 3][m] = v.w;
            }
            #pragma unroll
            for (int rr = 0; rr < 2; ++rr) {
                int kk = b_row + rr * 8;
                *(float4*)&Bs[kk][b_col] =
                    *(const float4*)(wj + (size_t)(k0 + kk) * H_DIM + n0 + b_col);
            }
            __syncthreads();
            #pragma unroll
            for (int kk = 0; kk < BK; ++kk) {
                float a[8], bb[8];
                *(float4*)&a[0]  = *(const float4*)&As[kk][ty * 8];
                *(float4*)&a[4]  = *(const float4*)&As[kk][ty * 8 + 4];
                *(float4*)&bb[0] = *(const float4*)&Bs[kk][tx * 8];
                *(float4*)&bb[4] = *(const float4*)&Bs[kk][tx * 8 + 4];
                #pragma unroll
                for (int i = 0; i < 8; ++i) {
                    #pragma unroll
                    for (int ll = 0; ll < 8; ++ll)
                        acc[i][ll] = fmaf(a[i], bb[ll], acc[i][ll]);
                }
            }
            __syncthreads();
        }
    }

    float lp[8][3];
    #pragma unroll
    for (int i = 0; i < 8; ++i) { lp[i][0] = 0.f; lp[i][1] = 0.f; lp[i][2] = 0.f; }
    #pragma unroll
    for (int ll = 0; ll < 8; ++ll) {
        int n = n0 + tx * 8 + ll;
        float bias = b1[n];
        float w2m1 = w2[n * 3 + 2];
        float w20  = w2[n * 3 + 1];
        float w2p1 = w2[n * 3 + 0];
        #pragma unroll
        for (int i = 0; i < 8; ++i) {
            float v = acc[i][ll] + bias;
            float g = 0.5f * v * (1.f + erff(v * 0.70710678118654752f));
            lp[i][0] = fmaf(g, w2m1, lp[i][0]);
            lp[i][1] = fmaf(g, w20,  lp[i][1]);
            lp[i][2] = fmaf(g, w2p1, lp[i][2]);
        }
    }
    #pragma unroll
    for (int i = 0; i < 8; ++i) {
        #pragma unroll
        for (int d = 0; d < 3; ++d) {
            float v = lp[i][d];
            v += __shfl_xor(v, 1, 64);
            v += __shfl_xor(v, 2, 64);
            v += __shfl_xor(v, 4, 64);
            v += __shfl_xor(v, 8, 64);
            lp[i][d] = v;
        }
    }
    if (tx == 0) {
        #pragma unroll
        for (int i = 0; i < 8; ++i) {
            ld_lp[0][ty * 8 + i] = lp[i][0];
            ld_lp[1][ty * 8 + i] = lp[i][1];
            ld_lp[2][ty * 8 + i] = lp[i][2];
        }
    }
    __syncthreads();
    float* pout = partials + (size_t)(bm * NBN + bn) * QLEN;
    for (int q = tid; q < QLEN; q += 256) {
        int t = t0 + q - 1;
        if (t >= 0 && t < T_LEN) {
            float v = 0.f;
            if (q >= 1 && q <= BM) v += ld_lp[1][q - 1];
            if (q >= 2)            v += ld_lp[2][q - 2];
            if (q < BM)            v += ld_lp[0][q];
            pout[q] = v;
        }
    }
}

__global__ void k_reduce_logits(const float* __restrict__ partials,
                                const float* __restrict__ b2,
                                float* __restrict__ logits) {
    int M = blockIdx.x * 256 + threadIdx.x;
    if (M >= 4 * T_LEN) return;
    int t = M % T_LEN;
    int bm = M / BM;
    int q = (M % BM) + 1;
    float s = b2[0];
    #pragma unroll
    for (int bn = 0; bn < NBN; ++bn)
        s += partials[(size_t)(bm * NBN + bn) * QLEN + q];
    if ((M % BM) == 0 && t != 0) {
        #pragma unroll
        for (int bn = 0; bn < NBN; ++bn)
            s += partials[(size_t)((bm - 1) * NBN + bn) * QLEN + (QLEN - 1)];
    }
    if ((M % BM) == BM - 1 && t != T_LEN - 1) {
        #pragma unroll
        for (int bn = 0; bn < NBN; ++bn)
            s += partials[(size_t)((bm + 1) * NBN + bn) * QLEN + 0];
    }
    logits[M] = s;
}

// ---------------- launch ----------------
extern "C" void kernel_launch(void* const* d_in, const int* in_sizes, int n_in,
                              void* d_out, int out_size, void* d_ws, size_t ws_size,
                              hipStream_t stream) {
    const float* x  = (const float*)d_in[0];
    const float* w1 = (const float*)d_in[1];
    const float* b1 = (const float*)d_in[2];
    const float* w2 = (const float*)d_in[3];
    const float* b2 = (const float*)d_in[4];
    const float* nw = (const float*)d_in[5];
    float* out = (float*)d_out;

    const size_t XS_ELEMS = (size_t)4 * PADT * D_DIM;          // 33,562,624
    const size_t WS_ELEMS = (size_t)3 * 2 * H_DIM * D_DIM;     // 3,145,728
    const size_t P2_FLOATS = (size_t)NBM2 * NBN2 * QL2;        // 132,096
    const size_t NEED = XS_ELEMS * 2 * sizeof(f16) + WS_ELEMS * sizeof(f16)
                      + (P2_FLOATS + 4 * T_LEN) * sizeof(float);

    if (ws_size >= NEED) {
        f16* xh = (f16*)d_ws;
        f16* xls = xh + XS_ELEMS;
        f16* wsd = xls + XS_ELEMS;
        float* partials = (float*)(wsd + WS_ELEMS);
        float* logits = partials + P2_FLOATS;

        k_split_x<<<(int)(XS_ELEMS / 4 / 256), 256, 0, stream>>>(x, xh, xls);
        k_split_w<<<(3 * H_DIM * D_DIM + 255) / 256, 256, 0, stream>>>(w1, wsd);
        k_conv_gemm_f16<<<NBM2 * NBN2, 512, 0, stream>>>(xh, xls, wsd, b1, w2, partials);
        k_reduce2<<<(4 * T_LEN + 255) / 256, 256, 0, stream>>>(partials, b2, logits);
        k_finalize<<<2048, 256, 0, stream>>>(x, logits, nw, out);
    } else {
        float* w1t      = (float*)d_ws;
        float* partials = w1t + 3 * D_DIM * H_DIM;
        float* logits   = partials + (size_t)NBM * NBN * QLEN;

        k_transpose_w1<<<(3 * D_DIM * H_DIM + 255) / 256, 256, 0, stream>>>(w1, w1t);
        k_conv_gemm<<<dim3(NBM, NBN), 256, 0, stream>>>(x, w1t, b1, w2, partials);
        k_reduce_logits<<<(4 * T_LEN + 255) / 256, 256, 0, stream>>>(partials, b2, logits);
        k_finalize<<<2048, 256, 0, stream>>>(x, logits, nw, out);
    }
}